// Round 1
// baseline (35477.606 us; speedup 1.0000x reference)
//
#include <hip/hip_runtime.h>

// ============================================================================
// 3-layer stacked LSTM (T=2048), MI355X.
// Phases (stream-ordered): split weights -> lstm1 (persistent, 64 WG, fused
// input proj) -> GEMM2 (split-bf16 MFMA) -> lstm2 (persistent, 128 WG) ->
// GEMM3 -> lstm3 (persistent, 32 WG) -> FC.
// Cross-WG per-step sync: per-WG flag (device-scope relaxed atomics via LLC),
// release = vmcnt(0)-drain + s_barrier before flag store; h double-buffered.
// ============================================================================

#define T_STEPS 2048

using s8v   = __attribute__((ext_vector_type(8))) short;
using u16x8 = __attribute__((ext_vector_type(8))) unsigned short;
using f4v   = __attribute__((ext_vector_type(4))) float;

__device__ __forceinline__ unsigned short f2bf(float v) {
  unsigned u = __float_as_uint(v);
  u = (u + 0x7FFFu + ((u >> 16) & 1u)) >> 16;   // RNE
  return (unsigned short)u;
}
__device__ __forceinline__ float bf2f(unsigned short b) {
  return __uint_as_float(((unsigned)b) << 16);
}
__device__ __forceinline__ float sigm(float x) { return 1.0f / (1.0f + __expf(-x)); }
__device__ __forceinline__ float tanh_f(float x) {
  float ax = fabsf(x);
  float e = __expf(-2.0f * ax);
  float t = (1.0f - e) / (1.0f + e);
  return copysignf(t, x);
}
__device__ __forceinline__ void flag_store(unsigned* p, unsigned v) {
  __hip_atomic_store(p, v, __ATOMIC_RELAXED, __HIP_MEMORY_SCOPE_AGENT);
}
__device__ __forceinline__ unsigned flag_load(const unsigned* p) {
  return __hip_atomic_load(p, __ATOMIC_RELAXED, __HIP_MEMORY_SCOPE_AGENT);
}
__device__ __forceinline__ void hstore(float* p, float v) {
  __hip_atomic_store(p, v, __ATOMIC_RELAXED, __HIP_MEMORY_SCOPE_AGENT);
}
__device__ __forceinline__ unsigned long long hload64(const float* p) {
  return __hip_atomic_load((const unsigned long long*)p, __ATOMIC_RELAXED,
                           __HIP_MEMORY_SCOPE_AGENT);
}
__device__ __forceinline__ void spin_ge(const unsigned* p, unsigned tgt) {
  unsigned gcnt = 0;
  while (flag_load(p) < tgt) {
    if (++gcnt > (1u << 18)) break;           // parachute against deadlock
    __builtin_amdgcn_s_sleep(2);
  }
}

// ============================================================================
// lstm1: 21 channels x H=256, shared weights. 64 WGs x 256 thr.
// WG w owns units [4w,4w+4) for all channels: 16 gate rows.
// thread = (r 0..15, q 0..15): Whh row chunk of 16 + Wih row chunk of 4 in regs.
// Input projection (K=64) fused; x(t+1) prefetched to regs.
// ============================================================================
__global__ __launch_bounds__(256, 1) void lstm1_kernel(
    const float* __restrict__ x,     // [2048,64,21]
    const float* __restrict__ Wih,   // [1024,64]
    const float* __restrict__ Whh,   // [1024,256]
    const float* __restrict__ bih, const float* __restrict__ bhh,
    float* __restrict__ hcur,        // [2][5376]
    unsigned short* __restrict__ h1hi, unsigned short* __restrict__ h1lo, // [2048,5376]
    unsigned* __restrict__ flags)    // [64]
{
  const int w = blockIdx.x;
  const int tid = threadIdx.x;
  const int r = tid >> 4;     // 0..15 : local gate-row
  const int q = tid & 15;     // 0..15 : k-chunk
  const int jl = r & 3, g = r >> 2;
  const int grow = (4 * w + jl) + 256 * g;

  float wh[16], wx[4];
#pragma unroll
  for (int j = 0; j < 16; ++j) wh[j] = Whh[grow * 256 + q * 16 + j];
#pragma unroll
  for (int j = 0; j < 4; ++j) wx[j] = Wih[grow * 64 + q * 4 + j];
  const float bias = bih[grow] + bhh[grow];

  __shared__ float xs[1344];          // x(t) as [k][ch]
  __shared__ float hs[16 * 338];      // h(t-1): [q][ch][16], stride 338 (bank-spread)
  __shared__ float zs[16][21];

  const int fch = tid >> 2, fjl = tid & 3;
  const bool fin = (tid < 84);
  float cst = 0.0f;

  float xpre[6];
#pragma unroll
  for (int i = 0; i < 6; ++i) {
    int idx = tid + 256 * i;
    xpre[i] = (idx < 1344) ? x[idx] : 0.0f;
  }

  for (int t = 0; t < T_STEPS; ++t) {
    // xs <- prefetched x(t); prefetch x(t+1)
#pragma unroll
    for (int i = 0; i < 6; ++i) {
      int idx = tid + 256 * i;
      if (idx < 1344) xs[idx] = xpre[i];
    }
    if (t + 1 < T_STEPS) {
      const float* xp = x + (size_t)(t + 1) * 1344;
#pragma unroll
      for (int i = 0; i < 6; ++i) {
        int idx = tid + 256 * i;
        if (idx < 1344) xpre[i] = xp[idx];
      }
    }
    if (t > 0 && tid < 64) spin_ge(&flags[tid], (unsigned)t);
    __syncthreads();
    {  // h(t-1) -> LDS (5376 f32 = 2688 u64, LLC loads)
      const float* hsrc = hcur + ((t + 1) & 1) * 5376;
#pragma unroll
      for (int i = 0; i < 11; ++i) {
        int p = tid + 256 * i;
        if (p < 2688) {
          unsigned long long v = hload64(hsrc + 2 * p);
          int k = (2 * p) & 255, ch = (2 * p) >> 8;
          int d = (k >> 4) * 338 + ch * 16 + (k & 15);
          union { unsigned long long u; float f[2]; } cc; cc.u = v;
          hs[d] = cc.f[0]; hs[d + 1] = cc.f[1];
        }
      }
    }
    __syncthreads();
    for (int ch = 0; ch < 21; ++ch) {
      const float* hp = &hs[q * 338 + ch * 16];
      float a = 0.0f;
#pragma unroll
      for (int j = 0; j < 16; ++j) a = fmaf(wh[j], hp[j], a);
#pragma unroll
      for (int j = 0; j < 4; ++j) a = fmaf(wx[j], xs[(q * 4 + j) * 21 + ch], a);
      a += __shfl_xor(a, 1); a += __shfl_xor(a, 2);
      a += __shfl_xor(a, 4); a += __shfl_xor(a, 8);
      if (q == 0) zs[r][ch] = a + bias;
    }
    __syncthreads();
    if (fin) {  // 84 tasks: (ch, unit)
      float zi = zs[fjl][fch], zf = zs[4 + fjl][fch];
      float zg = zs[8 + fjl][fch], zo = zs[12 + fjl][fch];
      float cn = sigm(zf) * cst + sigm(zi) * tanh_f(zg);
      float hn = sigm(zo) * tanh_f(cn);
      cst = cn;
      int hidx = fch * 256 + 4 * w + fjl;
      hstore(hcur + (t & 1) * 5376 + hidx, hn);
      unsigned short hb = f2bf(hn);
      h1hi[(size_t)t * 5376 + hidx] = hb;
      h1lo[(size_t)t * 5376 + hidx] = f2bf(hn - bf2f(hb));
    }
    asm volatile("s_waitcnt vmcnt(0)" ::: "memory");
    __syncthreads();   // all stores drained in every lane before flag
    if (tid == 0) flag_store(&flags[w], (unsigned)(t + 1));
  }
}

// ============================================================================
// lstm2/lstm3: batch-1 LSTM, hidden K_. NWG_ WGs x 256 thr; WG owns 8 units
// (32 gate rows); thread = (q 0..7, r 0..31), Whh chunk K_/8 in registers.
// xw (bias pre-folded by GEMM) prefetched per row by threads 0..31.
// ============================================================================
template <int K_, int NWG_, bool SPLIT_OUT>
__global__ __launch_bounds__(256, 1) void lstm_seq_kernel(
    const float* __restrict__ Whh,   // [4K_, K_]
    const float* __restrict__ xw,    // [2048, 4K_]
    float* __restrict__ hcur,        // [2][K_]
    unsigned short* __restrict__ hhi, unsigned short* __restrict__ hlo, // [2048,K_]
    float* __restrict__ hf32,        // [2048,K_]
    unsigned* __restrict__ flags)    // [NWG_]
{
  constexpr int CH = K_ / 8;
  const int w = blockIdx.x;
  const int tid = threadIdx.x;
  const int q = tid >> 5, r = tid & 31;
  const int jl = r & 7, g = r >> 3;
  const int grow = (8 * w + jl) + K_ * g;

  float wh[CH];
  {
    const float* wp = Whh + (size_t)grow * K_ + q * CH;
#pragma unroll
    for (int j = 0; j < CH; ++j) wh[j] = wp[j];
  }
  __shared__ float hs[K_];
  __shared__ float ps[8][32];

  float cst = 0.0f;
  float xwv = 0.0f;
  if (tid < 32) xwv = xw[grow];

  for (int t = 0; t < T_STEPS; ++t) {
    if (t > 0 && tid < NWG_) spin_ge(&flags[tid], (unsigned)t);
    __syncthreads();
    {
      const float* hsrc = hcur + ((t + 1) & 1) * K_;
      for (int p = tid; p < K_ / 2; p += 256) {
        unsigned long long v = hload64(hsrc + 2 * p);
        union { unsigned long long u; float f[2]; } cc; cc.u = v;
        hs[2 * p] = cc.f[0]; hs[2 * p + 1] = cc.f[1];
      }
    }
    __syncthreads();
    float a = 0.0f;
    {
      const float* hp = &hs[q * CH];   // broadcast reads (2 addrs/wave)
#pragma unroll
      for (int j = 0; j < CH; ++j) a = fmaf(wh[j], hp[j], a);
    }
    ps[q][r] = a;
    __syncthreads();
    if (tid < 32) {
      float z = xwv;
#pragma unroll
      for (int qq = 0; qq < 8; ++qq) z += ps[qq][tid];
      float zi = __shfl(z, jl);
      float zf = __shfl(z, 8 + jl);
      float zg = __shfl(z, 16 + jl);
      float zo = __shfl(z, 24 + jl);
      if (tid < 8) {
        float cn = sigm(zf) * cst + sigm(zi) * tanh_f(zg);
        float hn = sigm(zo) * tanh_f(cn);
        cst = cn;
        int hidx = 8 * w + tid;
        hstore(hcur + (t & 1) * K_ + hidx, hn);
        if constexpr (SPLIT_OUT) {
          unsigned short hb = f2bf(hn);
          hhi[(size_t)t * K_ + hidx] = hb;
          hlo[(size_t)t * K_ + hidx] = f2bf(hn - bf2f(hb));
        } else {
          hf32[(size_t)t * K_ + hidx] = hn;
        }
      }
      if (t + 1 < T_STEPS) xwv = xw[(size_t)(t + 1) * (4 * K_) + grow];
    }
    asm volatile("s_waitcnt vmcnt(0)" ::: "memory");
    __syncthreads();
    if (tid == 0) flag_store(&flags[w], (unsigned)(t + 1));
  }
}

// ============================================================================
// split fp32 -> (hi, lo) bf16
// ============================================================================
__global__ void split_kernel(const float* __restrict__ src,
                             unsigned short* __restrict__ hi,
                             unsigned short* __restrict__ lo, int n) {
  int i = blockIdx.x * 256 + threadIdx.x;
  if (i < n) {
    float v = src[i];
    unsigned short hb = f2bf(v);
    hi[i] = hb;
    lo[i] = f2bf(v - bf2f(hb));
  }
}

// ============================================================================
// Split-bf16 GEMM: C[M,N] = A[M,K] * Bt[N,K]^T + (b1+b2)[N], fp32 out.
// A,B pre-split hi/lo bf16. 128x128 tile, BK=32, 4 waves (2x2 of 64x64),
// mfma_f32_16x16x32_bf16 x3 (hi*hi, hi*lo, lo*hi). Reg-staged LDS + prefetch.
// ============================================================================
__global__ __launch_bounds__(256) void gemm_split_kernel(
    const unsigned short* __restrict__ Ah, const unsigned short* __restrict__ Al,
    const unsigned short* __restrict__ Bh, const unsigned short* __restrict__ Bl,
    const float* __restrict__ b1, const float* __restrict__ b2,
    float* __restrict__ C, int M, int N, int K)
{
  __shared__ __align__(16) unsigned short lds[16384];  // Ah|Al|Bh|Bl, each [128][32]
  const int mt = M >> 7;
  const int tm = blockIdx.x % mt, tn = blockIdx.x / mt;
  const size_t m0 = (size_t)tm * 128, n0 = (size_t)tn * 128;
  const int tid = threadIdx.x, lane = tid & 63, w = tid >> 6;
  const int wr = w >> 1, wc = w & 1;
  const int srow = tid >> 2, sc8 = (tid & 3) * 8;   // staging: rows srow, srow+64

  const unsigned short* pAh = Ah + m0 * K;
  const unsigned short* pAl = Al + m0 * K;
  const unsigned short* pBh = Bh + n0 * K;
  const unsigned short* pBl = Bl + n0 * K;

  f4v zero4 = {0.0f, 0.0f, 0.0f, 0.0f};
  f4v acc[4][4];
#pragma unroll
  for (int i = 0; i < 4; ++i)
#pragma unroll
    for (int j = 0; j < 4; ++j) acc[i][j] = zero4;

  u16x8 s0, s1, s2, s3, s4, s5, s6, s7;
#define LOADK(k0)                                                          \
  s0 = *(const u16x8*)(pAh + (size_t)srow * K + (k0) + sc8);               \
  s1 = *(const u16x8*)(pAh + (size_t)(srow + 64) * K + (k0) + sc8);        \
  s2 = *(const u16x8*)(pAl + (size_t)srow * K + (k0) + sc8);               \
  s3 = *(const u16x8*)(pAl + (size_t)(srow + 64) * K + (k0) + sc8);        \
  s4 = *(const u16x8*)(pBh + (size_t)srow * K + (k0) + sc8);               \
  s5 = *(const u16x8*)(pBh + (size_t)(srow + 64) * K + (k0) + sc8);        \
  s6 = *(const u16x8*)(pBl + (size_t)srow * K + (k0) + sc8);               \
  s7 = *(const u16x8*)(pBl + (size_t)(srow + 64) * K + (k0) + sc8);

  LOADK(0);
  const int fr = lane & 15, fko = (lane >> 4) * 8;
  for (int k0 = 0; k0 < K; k0 += 32) {
    *(u16x8*)&lds[0     +  srow       * 32 + sc8] = s0;
    *(u16x8*)&lds[0     + (srow + 64) * 32 + sc8] = s1;
    *(u16x8*)&lds[4096  +  srow       * 32 + sc8] = s2;
    *(u16x8*)&lds[4096  + (srow + 64) * 32 + sc8] = s3;
    *(u16x8*)&lds[8192  +  srow       * 32 + sc8] = s4;
    *(u16x8*)&lds[8192  + (srow + 64) * 32 + sc8] = s5;
    *(u16x8*)&lds[12288 +  srow       * 32 + sc8] = s6;
    *(u16x8*)&lds[12288 + (srow + 64) * 32 + sc8] = s7;
    __syncthreads();
    if (k0 + 32 < K) { LOADK(k0 + 32); }   // prefetch overlaps MFMA below
    s8v afh[4], afl[4], bfh[4], bfl[4];
#pragma unroll
    for (int i = 0; i < 4; ++i) {
      int ar = (64 * wr + 16 * i + fr) * 32 + fko;
      int br = (64 * wc + 16 * i + fr) * 32 + fko;
      afh[i] = *(const s8v*)&lds[0 + ar];
      afl[i] = *(const s8v*)&lds[4096 + ar];
      bfh[i] = *(const s8v*)&lds[8192 + br];
      bfl[i] = *(const s8v*)&lds[12288 + br];
    }
#pragma unroll
    for (int mi = 0; mi < 4; ++mi)
#pragma unroll
      for (int ni = 0; ni < 4; ++ni) {
        acc[mi][ni] = __builtin_amdgcn_mfma_f32_16x16x32_bf16(afh[mi], bfh[ni], acc[mi][ni], 0, 0, 0);
        acc[mi][ni] = __builtin_amdgcn_mfma_f32_16x16x32_bf16(afh[mi], bfl[ni], acc[mi][ni], 0, 0, 0);
        acc[mi][ni] = __builtin_amdgcn_mfma_f32_16x16x32_bf16(afl[mi], bfh[ni], acc[mi][ni], 0, 0, 0);
      }
    __syncthreads();
  }
#undef LOADK
  // epilogue: D col = lane&15, row = (lane>>4)*4 + rr   [m89-verified layout]
  const int er = (lane >> 4) * 4, ec = lane & 15;
#pragma unroll
  for (int ni = 0; ni < 4; ++ni) {
    size_t col = n0 + 64 * wc + 16 * ni + ec;
    float bv = b1[col] + b2[col];
#pragma unroll
    for (int mi = 0; mi < 4; ++mi) {
      size_t row = m0 + 64 * wr + 16 * mi + er;
#pragma unroll
      for (int rr = 0; rr < 4; ++rr)
        C[(row + rr) * N + col] = acc[mi][ni][rr] + bv;
    }
  }
}

// ============================================================================
// FC: out[t,m] = h3[t,:] . Wfc[m,:] + bfc[m]
// ============================================================================
__global__ void fc_kernel(const float* __restrict__ h3, const float* __restrict__ Wfc,
                          const float* __restrict__ bfc, float* __restrict__ out) {
  int t = blockIdx.x, m = threadIdx.x;
  if (m < 21) {
    const float* hp = h3 + (size_t)t * 256;
    const float* wp = Wfc + m * 256;
    float a = 0.0f;
#pragma unroll 8
    for (int j = 0; j < 256; ++j) a = fmaf(wp[j], hp[j], a);
    out[t * 21 + m] = a + bfc[m];
  }
}

// ============================================================================
// launch
// ============================================================================
extern "C" void kernel_launch(void* const* d_in, const int* in_sizes, int n_in,
                              void* d_out, int out_size, void* d_ws, size_t ws_size,
                              hipStream_t stream) {
  const float* x    = (const float*)d_in[0];
  const float* Wih1 = (const float*)d_in[1];
  const float* Whh1 = (const float*)d_in[2];
  const float* bih1 = (const float*)d_in[3];
  const float* bhh1 = (const float*)d_in[4];
  const float* Wih2 = (const float*)d_in[5];
  const float* Whh2 = (const float*)d_in[6];
  const float* bih2 = (const float*)d_in[7];
  const float* bhh2 = (const float*)d_in[8];
  const float* Wih3 = (const float*)d_in[9];
  const float* Whh3 = (const float*)d_in[10];
  const float* bih3 = (const float*)d_in[11];
  const float* bhh3 = (const float*)d_in[12];
  const float* Wfc  = (const float*)d_in[13];
  const float* bfc  = (const float*)d_in[14];
  float* out = (float*)d_out;

  // workspace layout (bytes; all 256-aligned)
  const size_t WS_NEEDED = 188809216;
  if (ws_size < WS_NEEDED) return;   // deterministic clean failure
  char* ws = (char*)d_ws;
  unsigned* flags1 = (unsigned*)(ws + 0);
  unsigned* flags2 = (unsigned*)(ws + 1024);
  unsigned* flags3 = (unsigned*)(ws + 2048);
  float* hcur1 = (float*)(ws + 4096);     // 2*5376 f32
  float* hcur2 = (float*)(ws + 49152);    // 2*1024 f32
  float* hcur3 = (float*)(ws + 61440);    // 2*256 f32
  unsigned short* wih2h = (unsigned short*)(ws + 65536);
  unsigned short* wih2l = (unsigned short*)(ws + 44105728);
  unsigned short* wih3h = (unsigned short*)(ws + 88145920);
  unsigned short* wih3l = (unsigned short*)(ws + 90243072);
  unsigned short* h1h   = (unsigned short*)(ws + 92340224);
  unsigned short* h1l   = (unsigned short*)(ws + 114360320);
  unsigned short* h2h   = (unsigned short*)(ws + 136380416);
  unsigned short* h2l   = (unsigned short*)(ws + 140574720);
  float* xw2 = (float*)(ws + 144769024);  // [2048,4096]
  float* xw3 = (float*)(ws + 178323456);  // [2048,1024]
  float* h3  = (float*)(ws + 186712064);  // [2048,256]

  hipMemsetAsync(ws, 0, 65536, stream);   // flags + hcur zero, every call

  const int nW2 = 4096 * 5376;
  split_kernel<<<(nW2 + 255) / 256, 256, 0, stream>>>(Wih2, wih2h, wih2l, nW2);
  const int nW3 = 1024 * 1024;
  split_kernel<<<(nW3 + 255) / 256, 256, 0, stream>>>(Wih3, wih3h, wih3l, nW3);

  lstm1_kernel<<<64, 256, 0, stream>>>(x, Wih1, Whh1, bih1, bhh1,
                                       hcur1, h1h, h1l, flags1);

  gemm_split_kernel<<<(2048 / 128) * (4096 / 128), 256, 0, stream>>>(
      h1h, h1l, wih2h, wih2l, bih2, bhh2, xw2, 2048, 4096, 5376);

  lstm_seq_kernel<1024, 128, true><<<128, 256, 0, stream>>>(
      Whh2, xw2, hcur2, h2h, h2l, (float*)nullptr, flags2);

  gemm_split_kernel<<<(2048 / 128) * (1024 / 128), 256, 0, stream>>>(
      h2h, h2l, wih3h, wih3l, bih3, bhh3, xw3, 2048, 1024, 1024);

  lstm_seq_kernel<256, 32, false><<<32, 256, 0, stream>>>(
      Whh3, xw3, hcur3, (unsigned short*)nullptr, (unsigned short*)nullptr, h3, flags3);

  fc_kernel<<<2048, 64, 0, stream>>>(h3, Wfc, bfc, out);
}

// Round 2
// 17024.248 us; speedup vs baseline: 2.0839x; 2.0839x over previous
//
#include <hip/hip_runtime.h>

// ============================================================================
// 3-layer stacked LSTM (T=2048), MI355X — round 2.
// Sync redesign: tagged-data handshake. h values stored as (f32,val tag=t+1)
// u64 AGENT-scope atomics; consumers poll the data directly (single LLC round
// trip per step). lstm1 split into 21 independent 4-WG channel groups.
// ============================================================================

#define T_STEPS 2048

using f4v   = __attribute__((ext_vector_type(4))) float;
using s8v   = __attribute__((ext_vector_type(8))) short;
using u16x8 = __attribute__((ext_vector_type(8))) unsigned short;

union HU { unsigned long long u; unsigned v[2]; float f[2]; };

__device__ __forceinline__ unsigned short f2bf(float v) {
  unsigned u = __float_as_uint(v);
  u = (u + 0x7FFFu + ((u >> 16) & 1u)) >> 16;   // RNE
  return (unsigned short)u;
}
__device__ __forceinline__ float bf2f(unsigned short b) {
  return __uint_as_float(((unsigned)b) << 16);
}
__device__ __forceinline__ float sigm(float x) { return 1.0f / (1.0f + __expf(-x)); }
__device__ __forceinline__ float tanh_f(float x) {
  float ax = fabsf(x);
  float e = __expf(-2.0f * ax);
  float t = (1.0f - e) / (1.0f + e);
  return copysignf(t, x);
}
__device__ __forceinline__ unsigned long long ld_agent(const unsigned long long* p) {
  return __hip_atomic_load(p, __ATOMIC_RELAXED, __HIP_MEMORY_SCOPE_AGENT);
}
__device__ __forceinline__ void st_agent(unsigned long long* p, unsigned long long v) {
  __hip_atomic_store(p, v, __ATOMIC_RELAXED, __HIP_MEMORY_SCOPE_AGENT);
}
__device__ __forceinline__ float poll1(const unsigned long long* p, unsigned tgt) {
  HU c; c.u = ld_agent(p);
  unsigned n = 0;
  while (c.v[1] < tgt) {              // tags monotonically increase
    if (++n > (1u << 20)) break;      // parachute
    c.u = ld_agent(p);
  }
  return c.f[0];
}
__device__ __forceinline__ void store_tagged(unsigned long long* p, float v, unsigned tag) {
  HU c; c.f[0] = v; c.v[1] = tag;
  st_agent(p, c.u);
}

// ============================================================================
// lstm1: 21 channels x H=256, shared weights. 21 groups x 4 WGs x 256 thr.
// Thread owns one full gate row (256 Whh + 64 Wih f32 in VGPRs).
// Group-local tagged-h sync only (channels fully independent).
// ============================================================================
__global__ __launch_bounds__(256, 1) void lstm1_kernel(
    const float* __restrict__ x,     // [2048,64,21]
    const float* __restrict__ Wih,   // [1024,64]
    const float* __restrict__ Whh,   // [1024,256]
    const float* __restrict__ bih, const float* __restrict__ bhh,
    unsigned long long* __restrict__ hg,   // [2][21][256] tagged
    unsigned short* __restrict__ h1hi, unsigned short* __restrict__ h1lo) // [2048,5376]
{
  const int c = blockIdx.x >> 2, w = blockIdx.x & 3;
  const int tid = threadIdx.x;
  const int ul = tid & 63, g = tid >> 6;
  const int grow = 64 * w + ul + 256 * g;

  f4v wh4[64], wx4[16];
  const f4v* wsrc = (const f4v*)(Whh + (size_t)grow * 256);
#pragma unroll
  for (int j = 0; j < 64; ++j) wh4[j] = wsrc[j];
  const f4v* xsrc = (const f4v*)(Wih + (size_t)grow * 64);
#pragma unroll
  for (int j = 0; j < 16; ++j) wx4[j] = xsrc[j];
  const float bias = bih[grow] + bhh[grow];

  __shared__ __align__(16) float hs[256];
  __shared__ __align__(16) float xs[64];
  __shared__ float zs[256];

  float xpre = (tid < 64) ? x[(size_t)tid * 21 + c] : 0.0f;
  float cst = 0.0f;

  for (int t = 0; t < T_STEPS; ++t) {
    if (tid < 64) {
      xs[tid] = xpre;
      if (t + 1 < T_STEPS) xpre = x[(size_t)(t + 1) * 1344 + tid * 21 + c];
    }
    float hv = poll1(&hg[((t + 1) & 1) * 5376 + c * 256 + tid], (unsigned)t);
    hs[tid] = hv;
    __syncthreads();
    float a0 = 0, a1 = 0, a2 = 0, a3 = 0;
    const f4v* hsv = (const f4v*)hs;
#pragma unroll
    for (int j = 0; j < 64; ++j) {
      f4v h4 = hsv[j];                 // wave-uniform addr: LDS broadcast
      a0 = fmaf(wh4[j][0], h4[0], a0);
      a1 = fmaf(wh4[j][1], h4[1], a1);
      a2 = fmaf(wh4[j][2], h4[2], a2);
      a3 = fmaf(wh4[j][3], h4[3], a3);
    }
    const f4v* xsv = (const f4v*)xs;
#pragma unroll
    for (int j = 0; j < 16; ++j) {
      f4v x4 = xsv[j];
      a0 = fmaf(wx4[j][0], x4[0], a0);
      a1 = fmaf(wx4[j][1], x4[1], a1);
      a2 = fmaf(wx4[j][2], x4[2], a2);
      a3 = fmaf(wx4[j][3], x4[3], a3);
    }
    zs[tid] = (a0 + a1) + (a2 + a3) + bias;
    __syncthreads();
    if (tid < 64) {
      float zi = zs[tid], zf = zs[tid + 64], zg = zs[tid + 128], zo = zs[tid + 192];
      float cn = sigm(zf) * cst + sigm(zi) * tanh_f(zg);
      float hn = sigm(zo) * tanh_f(cn);
      cst = cn;
      int idx = c * 256 + 64 * w + tid;
      store_tagged(&hg[(t & 1) * 5376 + idx], hn, (unsigned)(t + 1));
      unsigned short hb = f2bf(hn);
      h1hi[(size_t)t * 5376 + idx] = hb;
      h1lo[(size_t)t * 5376 + idx] = f2bf(hn - bf2f(hb));
    }
  }
}

// ============================================================================
// lstm2: H2=1024. 64 WGs x 256 thr; thread = (row-local rl 0..63, q 0..3),
// quarter-row (256 Whh f32) in VGPRs; shfl-reduce over q; WG owns 16 units.
// ============================================================================
__global__ __launch_bounds__(256, 1) void lstm2_kernel(
    const float* __restrict__ Whh,   // [4096,1024]
    const float* __restrict__ xw,    // [2048,4096] bias pre-folded
    unsigned long long* __restrict__ hg,   // [2][1024] tagged
    unsigned short* __restrict__ hhi, unsigned short* __restrict__ hlo)  // [2048,1024]
{
  const int bw = blockIdx.x;
  const int tid = threadIdx.x;
  const int q = tid & 3, rl = tid >> 2;
  const int ul = rl & 15, g = rl >> 4;
  const int grow = 16 * bw + ul + 1024 * g;

  f4v wh4[64];
  const f4v* wsrc = (const f4v*)(Whh + (size_t)grow * 1024 + q * 256);
#pragma unroll
  for (int j = 0; j < 64; ++j) wh4[j] = wsrc[j];

  __shared__ __align__(16) float hsp[4 * 264];   // stride 264: conflict-free 4-addr reads
  __shared__ float zs[64];

  float cst = 0.0f;
  float xwv = (q == 0) ? xw[grow] : 0.0f;
  const int pk = tid * 4;          // polled base index (4 consecutive h)
  const int pq = tid >> 6, pj = pk & 255;

  for (int t = 0; t < T_STEPS; ++t) {
    const unsigned tgt = (unsigned)t;
    const unsigned long long* pp = &hg[((t + 1) & 1) * 1024 + pk];
    HU c0, c1, c2, c3;
    c0.u = ld_agent(pp + 0); c1.u = ld_agent(pp + 1);
    c2.u = ld_agent(pp + 2); c3.u = ld_agent(pp + 3);
    unsigned n = 0;
    while (c0.v[1] < tgt || c1.v[1] < tgt || c2.v[1] < tgt || c3.v[1] < tgt) {
      if (++n > (1u << 20)) break;
      c0.u = ld_agent(pp + 0); c1.u = ld_agent(pp + 1);
      c2.u = ld_agent(pp + 2); c3.u = ld_agent(pp + 3);
    }
    f4v hv = { c0.f[0], c1.f[0], c2.f[0], c3.f[0] };
    *(f4v*)&hsp[pq * 264 + pj] = hv;
    __syncthreads();
    float a0 = 0, a1 = 0, a2 = 0, a3 = 0;
    const float* hb = &hsp[q * 264];
#pragma unroll
    for (int j = 0; j < 64; ++j) {
      f4v h4 = *(const f4v*)(hb + 4 * j);
      a0 = fmaf(wh4[j][0], h4[0], a0);
      a1 = fmaf(wh4[j][1], h4[1], a1);
      a2 = fmaf(wh4[j][2], h4[2], a2);
      a3 = fmaf(wh4[j][3], h4[3], a3);
    }
    float z = (a0 + a1) + (a2 + a3);
    z += __shfl_xor(z, 1);
    z += __shfl_xor(z, 2);
    if (q == 0) zs[rl] = z + xwv;
    __syncthreads();
    if (tid < 16) {
      float zi = zs[tid], zf = zs[tid + 16], zg2 = zs[tid + 32], zo = zs[tid + 48];
      float cn = sigm(zf) * cst + sigm(zi) * tanh_f(zg2);
      float hn = sigm(zo) * tanh_f(cn);
      cst = cn;
      int idx = 16 * bw + tid;
      store_tagged(&hg[(t & 1) * 1024 + idx], hn, (unsigned)(t + 1));
      unsigned short hb2 = f2bf(hn);
      hhi[(size_t)t * 1024 + idx] = hb2;
      hlo[(size_t)t * 1024 + idx] = f2bf(hn - bf2f(hb2));
    }
    if (q == 0 && t + 1 < T_STEPS) xwv = xw[(size_t)(t + 1) * 4096 + grow];
  }
}

// ============================================================================
// lstm3: H=256. 4 WGs x 256 thr; thread owns one full gate row.
// ============================================================================
__global__ __launch_bounds__(256, 1) void lstm3_kernel(
    const float* __restrict__ Whh,   // [1024,256]
    const float* __restrict__ xw,    // [2048,1024] bias pre-folded
    unsigned long long* __restrict__ hg,   // [2][256] tagged
    float* __restrict__ hout)        // [2048,256]
{
  const int w = blockIdx.x;
  const int tid = threadIdx.x;
  const int ul = tid & 63, g = tid >> 6;
  const int grow = 64 * w + ul + 256 * g;

  f4v wh4[64];
  const f4v* wsrc = (const f4v*)(Whh + (size_t)grow * 256);
#pragma unroll
  for (int j = 0; j < 64; ++j) wh4[j] = wsrc[j];

  __shared__ __align__(16) float hs[256];
  __shared__ float zs[256];

  float cst = 0.0f;
  float xwv = xw[grow];

  for (int t = 0; t < T_STEPS; ++t) {
    float hv = poll1(&hg[((t + 1) & 1) * 256 + tid], (unsigned)t);
    hs[tid] = hv;
    __syncthreads();
    float a0 = 0, a1 = 0, a2 = 0, a3 = 0;
    const f4v* hsv = (const f4v*)hs;
#pragma unroll
    for (int j = 0; j < 64; ++j) {
      f4v h4 = hsv[j];
      a0 = fmaf(wh4[j][0], h4[0], a0);
      a1 = fmaf(wh4[j][1], h4[1], a1);
      a2 = fmaf(wh4[j][2], h4[2], a2);
      a3 = fmaf(wh4[j][3], h4[3], a3);
    }
    zs[tid] = (a0 + a1) + (a2 + a3) + xwv;
    __syncthreads();
    if (tid < 64) {
      float zi = zs[tid], zf = zs[tid + 64], zg = zs[tid + 128], zo = zs[tid + 192];
      float cn = sigm(zf) * cst + sigm(zi) * tanh_f(zg);
      float hn = sigm(zo) * tanh_f(cn);
      cst = cn;
      int idx = 64 * w + tid;
      store_tagged(&hg[(t & 1) * 256 + idx], hn, (unsigned)(t + 1));
      hout[(size_t)t * 256 + idx] = hn;
    }
    if (t + 1 < T_STEPS) xwv = xw[(size_t)(t + 1) * 1024 + grow];
  }
}

// ============================================================================
// split fp32 -> (hi, lo) bf16
// ============================================================================
__global__ void split_kernel(const float* __restrict__ src,
                             unsigned short* __restrict__ hi,
                             unsigned short* __restrict__ lo, int n) {
  int i = blockIdx.x * 256 + threadIdx.x;
  if (i < n) {
    float v = src[i];
    unsigned short hb = f2bf(v);
    hi[i] = hb;
    lo[i] = f2bf(v - bf2f(hb));
  }
}

// ============================================================================
// Split-bf16 GEMM: C[M,N] = A[M,K] * Bt[N,K]^T + (b1+b2)[N], fp32 out.
// 128x128 tile, BK=32, 4 waves, 3 MFMAs per fragment (hi*hi, hi*lo, lo*hi).
// ============================================================================
__global__ __launch_bounds__(256) void gemm_split_kernel(
    const unsigned short* __restrict__ Ah, const unsigned short* __restrict__ Al,
    const unsigned short* __restrict__ Bh, const unsigned short* __restrict__ Bl,
    const float* __restrict__ b1, const float* __restrict__ b2,
    float* __restrict__ C, int M, int N, int K)
{
  __shared__ __align__(16) unsigned short lds[16384];
  const int mt = M >> 7;
  const int tm = blockIdx.x % mt, tn = blockIdx.x / mt;
  const size_t m0 = (size_t)tm * 128, n0 = (size_t)tn * 128;
  const int tid = threadIdx.x, lane = tid & 63, w = tid >> 6;
  const int wr = w >> 1, wc = w & 1;
  const int srow = tid >> 2, sc8 = (tid & 3) * 8;

  const unsigned short* pAh = Ah + m0 * K;
  const unsigned short* pAl = Al + m0 * K;
  const unsigned short* pBh = Bh + n0 * K;
  const unsigned short* pBl = Bl + n0 * K;

  f4v zero4 = {0.0f, 0.0f, 0.0f, 0.0f};
  f4v acc[4][4];
#pragma unroll
  for (int i = 0; i < 4; ++i)
#pragma unroll
    for (int j = 0; j < 4; ++j) acc[i][j] = zero4;

  u16x8 s0, s1, s2, s3, s4, s5, s6, s7;
#define LOADK(k0)                                                          \
  s0 = *(const u16x8*)(pAh + (size_t)srow * K + (k0) + sc8);               \
  s1 = *(const u16x8*)(pAh + (size_t)(srow + 64) * K + (k0) + sc8);        \
  s2 = *(const u16x8*)(pAl + (size_t)srow * K + (k0) + sc8);               \
  s3 = *(const u16x8*)(pAl + (size_t)(srow + 64) * K + (k0) + sc8);        \
  s4 = *(const u16x8*)(pBh + (size_t)srow * K + (k0) + sc8);               \
  s5 = *(const u16x8*)(pBh + (size_t)(srow + 64) * K + (k0) + sc8);        \
  s6 = *(const u16x8*)(pBl + (size_t)srow * K + (k0) + sc8);               \
  s7 = *(const u16x8*)(pBl + (size_t)(srow + 64) * K + (k0) + sc8);

  LOADK(0);
  const int fr = lane & 15, fko = (lane >> 4) * 8;
  for (int k0 = 0; k0 < K; k0 += 32) {
    *(u16x8*)&lds[0     +  srow       * 32 + sc8] = s0;
    *(u16x8*)&lds[0     + (srow + 64) * 32 + sc8] = s1;
    *(u16x8*)&lds[4096  +  srow       * 32 + sc8] = s2;
    *(u16x8*)&lds[4096  + (srow + 64) * 32 + sc8] = s3;
    *(u16x8*)&lds[8192  +  srow       * 32 + sc8] = s4;
    *(u16x8*)&lds[8192  + (srow + 64) * 32 + sc8] = s5;
    *(u16x8*)&lds[12288 +  srow       * 32 + sc8] = s6;
    *(u16x8*)&lds[12288 + (srow + 64) * 32 + sc8] = s7;
    __syncthreads();
    if (k0 + 32 < K) { LOADK(k0 + 32); }
    s8v afh[4], afl[4], bfh[4], bfl[4];
#pragma unroll
    for (int i = 0; i < 4; ++i) {
      int ar = (64 * wr + 16 * i + fr) * 32 + fko;
      int br = (64 * wc + 16 * i + fr) * 32 + fko;
      afh[i] = *(const s8v*)&lds[0 + ar];
      afl[i] = *(const s8v*)&lds[4096 + ar];
      bfh[i] = *(const s8v*)&lds[8192 + br];
      bfl[i] = *(const s8v*)&lds[12288 + br];
    }
#pragma unroll
    for (int mi = 0; mi < 4; ++mi)
#pragma unroll
      for (int ni = 0; ni < 4; ++ni) {
        acc[mi][ni] = __builtin_amdgcn_mfma_f32_16x16x32_bf16(afh[mi], bfh[ni], acc[mi][ni], 0, 0, 0);
        acc[mi][ni] = __builtin_amdgcn_mfma_f32_16x16x32_bf16(afh[mi], bfl[ni], acc[mi][ni], 0, 0, 0);
        acc[mi][ni] = __builtin_amdgcn_mfma_f32_16x16x32_bf16(afl[mi], bfh[ni], acc[mi][ni], 0, 0, 0);
      }
    __syncthreads();
  }
#undef LOADK
  const int er = (lane >> 4) * 4, ec = lane & 15;
#pragma unroll
  for (int ni = 0; ni < 4; ++ni) {
    size_t col = n0 + 64 * wc + 16 * ni + ec;
    float bv = b1[col] + b2[col];
#pragma unroll
    for (int mi = 0; mi < 4; ++mi) {
      size_t row = m0 + 64 * wr + 16 * mi + er;
#pragma unroll
      for (int rr = 0; rr < 4; ++rr)
        C[(row + rr) * N + col] = acc[mi][ni][rr] + bv;
    }
  }
}

// ============================================================================
// FC: out[t,m] = h3[t,:] . Wfc[m,:] + bfc[m]
// ============================================================================
__global__ void fc_kernel(const float* __restrict__ h3, const float* __restrict__ Wfc,
                          const float* __restrict__ bfc, float* __restrict__ out) {
  int t = blockIdx.x, m = threadIdx.x;
  if (m < 21) {
    const float* hp = h3 + (size_t)t * 256;
    const float* wp = Wfc + m * 256;
    float a = 0.0f;
#pragma unroll 8
    for (int j = 0; j < 256; ++j) a = fmaf(wp[j], hp[j], a);
    out[t * 21 + m] = a + bfc[m];
  }
}

// ============================================================================
// launch
// ============================================================================
extern "C" void kernel_launch(void* const* d_in, const int* in_sizes, int n_in,
                              void* d_out, int out_size, void* d_ws, size_t ws_size,
                              hipStream_t stream) {
  const float* x    = (const float*)d_in[0];
  const float* Wih1 = (const float*)d_in[1];
  const float* Whh1 = (const float*)d_in[2];
  const float* bih1 = (const float*)d_in[3];
  const float* bhh1 = (const float*)d_in[4];
  const float* Wih2 = (const float*)d_in[5];
  const float* Whh2 = (const float*)d_in[6];
  const float* bih2 = (const float*)d_in[7];
  const float* bhh2 = (const float*)d_in[8];
  const float* Wih3 = (const float*)d_in[9];
  const float* Whh3 = (const float*)d_in[10];
  const float* bih3 = (const float*)d_in[11];
  const float* bhh3 = (const float*)d_in[12];
  const float* Wfc  = (const float*)d_in[13];
  const float* bfc  = (const float*)d_in[14];
  float* out = (float*)d_out;

  const size_t WS_NEEDED = 186753024;
  if (ws_size < WS_NEEDED) return;
  char* ws = (char*)d_ws;
  unsigned long long* hg1 = (unsigned long long*)(ws + 0);       // 2*5376*8 = 86016
  unsigned long long* hg2 = (unsigned long long*)(ws + 86016);   // 2*1024*8 = 16384
  unsigned long long* hg3 = (unsigned long long*)(ws + 102400);  // 2*256*8  = 4096
  unsigned short* wih2h = (unsigned short*)(ws + 106496);
  unsigned short* wih2l = (unsigned short*)(ws + 44146688);
  unsigned short* wih3h = (unsigned short*)(ws + 88186880);
  unsigned short* wih3l = (unsigned short*)(ws + 90284032);
  unsigned short* h1h   = (unsigned short*)(ws + 92381184);
  unsigned short* h1l   = (unsigned short*)(ws + 114401280);
  unsigned short* h2h   = (unsigned short*)(ws + 136421376);
  unsigned short* h2l   = (unsigned short*)(ws + 140615680);
  float* xw2 = (float*)(ws + 144809984);   // [2048,4096]
  float* xw3 = (float*)(ws + 178364416);   // [2048,1024]
  float* h3  = (float*)(ws + 106496);      // [2048,256] — aliases wih2h (GEMM2 done)

  hipMemsetAsync(ws, 0, 106496, stream);   // zero all tag buffers every call

  const int nW2 = 4096 * 5376;
  split_kernel<<<(nW2 + 255) / 256, 256, 0, stream>>>(Wih2, wih2h, wih2l, nW2);
  const int nW3 = 1024 * 1024;
  split_kernel<<<(nW3 + 255) / 256, 256, 0, stream>>>(Wih3, wih3h, wih3l, nW3);

  lstm1_kernel<<<84, 256, 0, stream>>>(x, Wih1, Whh1, bih1, bhh1, hg1, h1h, h1l);

  gemm_split_kernel<<<(2048 / 128) * (4096 / 128), 256, 0, stream>>>(
      h1h, h1l, wih2h, wih2l, bih2, bhh2, xw2, 2048, 4096, 5376);

  lstm2_kernel<<<64, 256, 0, stream>>>(Whh2, xw2, hg2, h2h, h2l);

  gemm_split_kernel<<<(2048 / 128) * (1024 / 128), 256, 0, stream>>>(
      h2h, h2l, wih3h, wih3l, bih3, bhh3, xw3, 2048, 1024, 1024);

  lstm3_kernel<<<4, 256, 0, stream>>>(Whh3, xw3, hg3, h3);

  fc_kernel<<<2048, 64, 0, stream>>>(h3, Wfc, bfc, out);
}